// Round 5
// baseline (1256.989 us; speedup 1.0000x reference)
//
#include <hip/hip_runtime.h>

// NerfModel: voxel-grid gather + SH-deg2 eval.
//   inputs : x (M,3) f32, d (M,3) f32, voxel_grid (200,200,200,28) f32
//   outputs: color (M,3) f32 then sigma (M,) f32, concatenated in d_out.
//
// Ladder so far:
//   R0 single-kernel random gather:                 1087 us (0.4 TB/s random regime)
//   R2 (i0,i1)-sorted gather works (~250-350 us) but global returning atomics
//      in the scatter cost 945 us.
//   R3 two-stage LDS-atomic sort: contended atomics gone, but per-slab stage B
//      ran on only 200 blocks (~3 waves/CU device-wide) -> ~500 us.
//   R4 stage B split into 16 chunks/slab (3200 blocks) -- infra failure, no data.
// R5 = identical resubmit of R4.

constexpr float kScale = 1.5f;
constexpr int   kN     = 200;
constexpr int   kNB    = 256;    // i0 buckets (200 used)
constexpr int   kNBLK  = 2048;   // block count for count/scatter passes
constexpr int   kBT    = 256;    // threads per block
constexpr int   kC     = 16;     // chunks per slab in stage B

__device__ __forceinline__ bool point_to_voxel(float x0, float x1, float x2,
                                               int& bucket, int& voff) {
    const bool mask = (fabsf(x0) < kScale) && (fabsf(x1) < kScale) && (fabsf(x2) < kScale);
    if (!mask) return false;
    const float h = 2.0f * kScale / (float)kN;   // 0.015f
    int i0 = (int)(x0 / h + 0.5f * (float)kN);
    int i1 = (int)(x1 / h + 0.5f * (float)kN);
    int i2 = (int)(x2 / h + 0.5f * (float)kN);
    i0 = min(max(i0, 0), kN - 1);
    i1 = min(max(i1, 0), kN - 1);
    i2 = min(max(i2, 0), kN - 1);
    bucket = i0;
    voff   = (i0 * kN + i1) * kN + i2;
    return true;
}

// ---- Pass 1: per-block i0 histogram; zero outputs for unmasked points ----
__global__ __launch_bounds__(kBT) void k_count(const float* __restrict__ x,
                                               float* __restrict__ out, int M,
                                               int* __restrict__ ghist) {
    __shared__ int h[kNB];
    for (int t = threadIdx.x; t < kNB; t += kBT) h[t] = 0;
    __syncthreads();
    const int stride = kNBLK * kBT;
    for (int i = blockIdx.x * kBT + threadIdx.x; i < M; i += stride) {
        const float x0 = x[3 * i + 0];
        const float x1 = x[3 * i + 1];
        const float x2 = x[3 * i + 2];
        int b, voff;
        if (point_to_voxel(x0, x1, x2, b, voff)) {
            atomicAdd(&h[b], 1);
        } else {
            out[3 * i + 0] = 0.0f;
            out[3 * i + 1] = 0.0f;
            out[3 * i + 2] = 0.0f;
            out[(size_t)3 * M + i] = 0.0f;
        }
    }
    __syncthreads();
    for (int t = threadIdx.x; t < kNB; t += kBT) ghist[blockIdx.x * kNB + t] = h[t];
}

// ---- Pass 2: per-bucket exclusive scan across blocks (one block per bucket) ----
__global__ __launch_bounds__(kBT) void k_scan_blocks(int* __restrict__ ghist,
                                                     int* __restrict__ totals) {
    const int b = blockIdx.x;
    __shared__ int sums[kBT];
    constexpr int per = kNBLK / kBT;   // 8
    const int base = threadIdx.x * per;
    int local[per];
    int s = 0;
    for (int k = 0; k < per; ++k) { local[k] = ghist[(base + k) * kNB + b]; s += local[k]; }
    sums[threadIdx.x] = s;
    __syncthreads();
    for (int off = 1; off < kBT; off <<= 1) {           // Hillis-Steele inclusive
        int t = (threadIdx.x >= off) ? sums[threadIdx.x - off] : 0;
        __syncthreads();
        sums[threadIdx.x] += t;
        __syncthreads();
    }
    int run = sums[threadIdx.x] - s;                    // exclusive base for this chunk
    for (int k = 0; k < per; ++k) { const int c = local[k]; ghist[(base + k) * kNB + b] = run; run += c; }
    if (threadIdx.x == kBT - 1) totals[b] = sums[kBT - 1];
}

// ---- Pass 3: exclusive scan of bucket totals -> bases (+ grand total) ----
__global__ __launch_bounds__(kNB) void k_scan_buckets(const int* __restrict__ totals,
                                                      int* __restrict__ bases) {
    __shared__ int s[kNB];
    const int t = threadIdx.x;
    const int own = totals[t];
    s[t] = own;
    __syncthreads();
    for (int off = 1; off < kNB; off <<= 1) {
        int v = (t >= off) ? s[t - off] : 0;
        __syncthreads();
        s[t] += v;
        __syncthreads();
    }
    bases[t] = s[t] - own;
    if (t == kNB - 1) bases[kNB] = s[kNB - 1];          // total masked count
}

// ---- Pass 4: scatter masked points into i0-grouped arrays (LDS ranks only) ----
__global__ __launch_bounds__(kBT) void k_scatter0(const float* __restrict__ x,
                                                  const float* __restrict__ dir, int M,
                                                  const int* __restrict__ ghist,
                                                  const int* __restrict__ bases,
                                                  float4* __restrict__ payl0,
                                                  int* __restrict__ vox0) {
    __shared__ int cur[kNB];
    for (int t = threadIdx.x; t < kNB; t += kBT) cur[t] = 0;
    __syncthreads();
    const int stride = kNBLK * kBT;
    for (int i = blockIdx.x * kBT + threadIdx.x; i < M; i += stride) {
        const float x0 = x[3 * i + 0];
        const float x1 = x[3 * i + 1];
        const float x2 = x[3 * i + 2];
        int b, voff;
        if (point_to_voxel(x0, x1, x2, b, voff)) {
            const int r   = atomicAdd(&cur[b], 1);      // LDS atomic: fast
            const int pos = bases[b] + ghist[blockIdx.x * kNB + b] + r;
            payl0[pos] = make_float4(dir[3 * i + 0], dir[3 * i + 1], dir[3 * i + 2],
                                     __int_as_float(i));
            vox0[pos] = voff;
        }
    }
}

// ---- Stage B1: per-(slab,chunk) i1 histogram (reads vox0 only) ----
__global__ __launch_bounds__(kBT) void k_hist1(const int* __restrict__ vox0,
                                               const int* __restrict__ bases,
                                               int* __restrict__ ghist2) {
    const int s = blockIdx.x / kC;
    const int c = blockIdx.x % kC;
    const int beg = bases[s];
    const int len = bases[s + 1] - beg;
    const int lo = beg + (int)(((long long)len * c) / kC);
    const int hi = beg + (int)(((long long)len * (c + 1)) / kC);

    __shared__ int h[kN];
    for (int t = threadIdx.x; t < kN; t += kBT) h[t] = 0;
    __syncthreads();
    for (int j = lo + threadIdx.x; j < hi; j += kBT) {
        const int i1 = (vox0[j] / kN) % kN;
        atomicAdd(&h[i1], 1);
    }
    __syncthreads();
    for (int t = threadIdx.x; t < kN; t += kBT)
        ghist2[(size_t)blockIdx.x * kN + t] = h[t];
}

// ---- Stage B2: per-slab scan over (i1, chunk) -> absolute cursors ----
__global__ __launch_bounds__(kBT) void k_scan1(int* __restrict__ ghist2,
                                               const int* __restrict__ bases) {
    const int s = blockIdx.x;          // slab
    const int t = threadIdx.x;
    __shared__ int sc[kBT];

    int v[kC];
    int tot = 0;
    if (t < kN) {
        for (int c = 0; c < kC; ++c) {
            v[c] = ghist2[(size_t)(s * kC + c) * kN + t];
            tot += v[c];
        }
    }
    sc[t] = (t < kN) ? tot : 0;
    __syncthreads();
    for (int off = 1; off < kBT; off <<= 1) {          // inclusive scan over i1
        const int u = (t >= off) ? sc[t - off] : 0;
        __syncthreads();
        sc[t] += u;
        __syncthreads();
    }
    if (t < kN) {
        int off0 = bases[s] + sc[t] - tot;             // exclusive base for this i1
        for (int c = 0; c < kC; ++c) {
            ghist2[(size_t)(s * kC + c) * kN + t] = off0;
            off0 += v[c];
        }
    }
}

// ---- Stage B3: per-chunk LDS-cursor scatter into (i0,i1)-grouped arrays ----
__global__ __launch_bounds__(kBT) void k_scatter1(const float4* __restrict__ payl0,
                                                  const int* __restrict__ vox0,
                                                  float4* __restrict__ payl1,
                                                  int* __restrict__ vox1,
                                                  const int* __restrict__ bases,
                                                  const int* __restrict__ ghist2) {
    const int s = blockIdx.x / kC;
    const int c = blockIdx.x % kC;
    const int beg = bases[s];
    const int len = bases[s + 1] - beg;
    const int lo = beg + (int)(((long long)len * c) / kC);
    const int hi = beg + (int)(((long long)len * (c + 1)) / kC);

    __shared__ int cur[kN];
    for (int t = threadIdx.x; t < kN; t += kBT)
        cur[t] = ghist2[(size_t)blockIdx.x * kN + t];
    __syncthreads();
    for (int j = lo + threadIdx.x; j < hi; j += kBT) {
        const int v  = vox0[j];
        const int i1 = (v / kN) % kN;
        const int pos = atomicAdd(&cur[i1], 1);        // LDS atomic
        payl1[pos] = payl0[j];
        vox1[pos]  = v;
    }
}

// ---- Pass 6: address-ordered gather + SH eval over the sorted list ----
__global__ __launch_bounds__(kBT) void k_gather(const float4* __restrict__ payload,
                                                const int* __restrict__ voxarr,
                                                const float* __restrict__ grid,
                                                float* __restrict__ out, int M,
                                                const int* __restrict__ bases) {
    const int j = blockIdx.x * kBT + threadIdx.x;
    if (j >= bases[kNB]) return;

    const float4 p = payload[j];
    const int i = __float_as_int(p.w);
    const size_t voff = (size_t)voxarr[j] * 28u;
    const float4* __restrict__ g4 = reinterpret_cast<const float4*>(grid + voff);
    const float4 t0 = g4[0];
    const float4 t1 = g4[1];
    const float4 t2 = g4[2];
    const float4 t3 = g4[3];
    const float4 t4 = g4[4];
    const float4 t5 = g4[5];
    const float4 t6 = g4[6];
    const float t[28] = {
        t0.x, t0.y, t0.z, t0.w,
        t1.x, t1.y, t1.z, t1.w,
        t2.x, t2.y, t2.z, t2.w,
        t3.x, t3.y, t3.z, t3.w,
        t4.x, t4.y, t4.z, t4.w,
        t5.x, t5.y, t5.z, t5.w,
        t6.x, t6.y, t6.z, t6.w
    };

    const float sg = fmaxf(t[0], 0.0f);

    const float dx = p.x, dy = p.y, dz = p.z;
    const float b0 = 0.282095f;
    const float b1 = -0.488603f * dy;
    const float b2 =  0.488603f * dz;
    const float b3 = -0.488603f * dx;
    const float b4 =  1.092548f * dx * dy;
    const float b5 = -1.092548f * dy * dz;
    const float b6 =  0.315392f * (2.0f * dz * dz - dx * dx - dy * dy);
    const float b7 = -1.092548f * dx * dz;
    const float b8 =  0.546274f * (dx * dx - dy * dy);

    const float c0 = b0 * t[1]  + b1 * t[2]  + b2 * t[3]  + b3 * t[4]  + b4 * t[5]
                   + b5 * t[6]  + b6 * t[7]  + b7 * t[8]  + b8 * t[9];
    const float c1 = b0 * t[10] + b1 * t[11] + b2 * t[12] + b3 * t[13] + b4 * t[14]
                   + b5 * t[15] + b6 * t[16] + b7 * t[17] + b8 * t[18];
    const float c2 = b0 * t[19] + b1 * t[20] + b2 * t[21] + b3 * t[22] + b4 * t[23]
                   + b5 * t[24] + b6 * t[25] + b7 * t[26] + b8 * t[27];

    out[3 * i + 0] = c0;
    out[3 * i + 1] = c1;
    out[3 * i + 2] = c2;
    out[(size_t)3 * M + i] = sg;
}

// ---- Fallback: the original verified single-kernel path (ws too small) ----
__global__ __launch_bounds__(kBT) void nerf_fwd(
    const float* __restrict__ x,
    const float* __restrict__ dir,
    const float* __restrict__ grid,
    float* __restrict__ out, int M)
{
    int i = blockIdx.x * blockDim.x + threadIdx.x;
    if (i >= M) return;

    const float x0 = x[3 * i + 0];
    const float x1 = x[3 * i + 1];
    const float x2 = x[3 * i + 2];

    float c0 = 0.0f, c1 = 0.0f, c2 = 0.0f, sg = 0.0f;
    int b, voff;
    if (point_to_voxel(x0, x1, x2, b, voff)) {
        const float4* __restrict__ g4 = reinterpret_cast<const float4*>(grid + (size_t)voff * 28u);
        const float4 t0 = g4[0], t1 = g4[1], t2 = g4[2], t3 = g4[3], t4 = g4[4], t5 = g4[5], t6 = g4[6];
        const float t[28] = {
            t0.x, t0.y, t0.z, t0.w, t1.x, t1.y, t1.z, t1.w, t2.x, t2.y, t2.z, t2.w,
            t3.x, t3.y, t3.z, t3.w, t4.x, t4.y, t4.z, t4.w, t5.x, t5.y, t5.z, t5.w,
            t6.x, t6.y, t6.z, t6.w
        };
        sg = fmaxf(t[0], 0.0f);
        const float dx = dir[3 * i + 0], dy = dir[3 * i + 1], dz = dir[3 * i + 2];
        const float b0 = 0.282095f;
        const float b1 = -0.488603f * dy;
        const float b2 =  0.488603f * dz;
        const float b3 = -0.488603f * dx;
        const float b4 =  1.092548f * dx * dy;
        const float b5 = -1.092548f * dy * dz;
        const float b6 =  0.315392f * (2.0f * dz * dz - dx * dx - dy * dy);
        const float b7 = -1.092548f * dx * dz;
        const float b8 =  0.546274f * (dx * dx - dy * dy);
        c0 = b0*t[1]  + b1*t[2]  + b2*t[3]  + b3*t[4]  + b4*t[5]  + b5*t[6]  + b6*t[7]  + b7*t[8]  + b8*t[9];
        c1 = b0*t[10] + b1*t[11] + b2*t[12] + b3*t[13] + b4*t[14] + b5*t[15] + b6*t[16] + b7*t[17] + b8*t[18];
        c2 = b0*t[19] + b1*t[20] + b2*t[21] + b3*t[22] + b4*t[23] + b5*t[24] + b6*t[25] + b7*t[26] + b8*t[27];
    }
    out[3 * i + 0] = c0;
    out[3 * i + 1] = c1;
    out[3 * i + 2] = c2;
    out[(size_t)3 * M + i] = sg;
}

extern "C" void kernel_launch(void* const* d_in, const int* in_sizes, int n_in,
                              void* d_out, int out_size, void* d_ws, size_t ws_size,
                              hipStream_t stream) {
    const float* x    = (const float*)d_in[0];
    const float* dir  = (const float*)d_in[1];
    const float* grid = (const float*)d_in[2];
    float* out = (float*)d_out;

    const int M = in_sizes[0] / 3;   // 4194304

    // Workspace: payl0 (M f4) | payl1 (M f4) | vox0 (M int) | vox1 (M int)
    //          | ghist (kNBLK*kNB) | totals (kNB) | bases (kNB+1)
    //          | ghist2 (kN*kC*kN)                                   ~= 173 MB
    const size_t need = (size_t)M * 16 * 2 + (size_t)M * 4 * 2
                      + (size_t)kNBLK * kNB * 4 + (size_t)(2 * kNB + 1) * 4
                      + (size_t)kN * kC * kN * 4;
    if (d_ws == nullptr || ws_size < need) {
        const int grid_dim = (M + kBT - 1) / kBT;
        nerf_fwd<<<grid_dim, kBT, 0, stream>>>(x, dir, grid, out, M);
        return;
    }

    float4* payl0 = (float4*)d_ws;
    float4* payl1 = payl0 + M;
    int* vox0   = (int*)(payl1 + M);
    int* vox1   = vox0 + M;
    int* ghist  = vox1 + M;
    int* totals = ghist + (size_t)kNBLK * kNB;
    int* bases  = totals + kNB;
    int* ghist2 = bases + (kNB + 1);

    k_count      <<<kNBLK, kBT, 0, stream>>>(x, out, M, ghist);
    k_scan_blocks<<<kNB,   kBT, 0, stream>>>(ghist, totals);
    k_scan_buckets<<<1,    kNB, 0, stream>>>(totals, bases);
    k_scatter0   <<<kNBLK, kBT, 0, stream>>>(x, dir, M, ghist, bases, payl0, vox0);
    k_hist1      <<<kN * kC, kBT, 0, stream>>>(vox0, bases, ghist2);
    k_scan1      <<<kN,    kBT, 0, stream>>>(ghist2, bases);
    k_scatter1   <<<kN * kC, kBT, 0, stream>>>(payl0, vox0, payl1, vox1, bases, ghist2);
    k_gather     <<<(M + kBT - 1) / kBT, kBT, 0, stream>>>(payl1, vox1, grid, out, M, bases);
}

// Round 6
// 1234.419 us; speedup vs baseline: 1.0183x; 1.0183x over previous
//
#include <hip/hip_runtime.h>

// NerfModel: voxel-grid gather + SH-deg2 eval.
//   inputs : x (M,3) f32, d (M,3) f32, voxel_grid (200,200,200,28) f32
//   outputs: color (M,3) f32 then sigma (M,) f32, concatenated in d_out.
//
// Ladder:
//   R0 single-kernel random gather:            1087 us (random-DRAM read regime)
//   R2 (i0,i1)-sorted gather: gather <=346 us, but scatter = 945 us.
//   R3/R5: LDS-atomic + parallel stage B: identical 1256/1257 us =>
//     stage B ~50 us in both; the real cost is k_scatter0 ~880 us:
//     per-instruction scattered 16B/4B writes (64 lanes -> 64 lines) +
//     write-allocate amplification. Same random-DRAM regime, write side.
//   R6 (this): k_scatter0 becomes an LDS-staged block counting sort; flush
//     writes bucket-runs contiguously so each wave-store coalesces.

constexpr float kScale = 1.5f;
constexpr int   kN     = 200;
constexpr int   kNB    = 256;    // i0 buckets (200 used)
constexpr int   kNBLK  = 2048;   // block count for count/scatter passes
constexpr int   kBT    = 256;    // threads per block
constexpr int   kC     = 16;     // chunks per slab in stage B
constexpr int   kIt    = 8;      // points per thread in count/scatter (M = kNBLK*kBT*kIt)
constexpr int   kTile  = kBT * kIt;  // 2048 points staged per block

__device__ __forceinline__ bool point_to_voxel(float x0, float x1, float x2,
                                               int& bucket, int& voff) {
    const bool mask = (fabsf(x0) < kScale) && (fabsf(x1) < kScale) && (fabsf(x2) < kScale);
    if (!mask) return false;
    const float h = 2.0f * kScale / (float)kN;   // 0.015f
    int i0 = (int)(x0 / h + 0.5f * (float)kN);
    int i1 = (int)(x1 / h + 0.5f * (float)kN);
    int i2 = (int)(x2 / h + 0.5f * (float)kN);
    i0 = min(max(i0, 0), kN - 1);
    i1 = min(max(i1, 0), kN - 1);
    i2 = min(max(i2, 0), kN - 1);
    bucket = i0;
    voff   = (i0 * kN + i1) * kN + i2;
    return true;
}

// ---- Pass 1: per-block i0 histogram; zero outputs for unmasked points ----
__global__ __launch_bounds__(kBT) void k_count(const float* __restrict__ x,
                                               float* __restrict__ out, int M,
                                               int* __restrict__ ghist) {
    __shared__ int h[kNB];
    for (int t = threadIdx.x; t < kNB; t += kBT) h[t] = 0;
    __syncthreads();
    const int stride = kNBLK * kBT;
    for (int i = blockIdx.x * kBT + threadIdx.x; i < M; i += stride) {
        const float x0 = x[3 * i + 0];
        const float x1 = x[3 * i + 1];
        const float x2 = x[3 * i + 2];
        int b, voff;
        if (point_to_voxel(x0, x1, x2, b, voff)) {
            atomicAdd(&h[b], 1);
        } else {
            out[3 * i + 0] = 0.0f;
            out[3 * i + 1] = 0.0f;
            out[3 * i + 2] = 0.0f;
            out[(size_t)3 * M + i] = 0.0f;
        }
    }
    __syncthreads();
    for (int t = threadIdx.x; t < kNB; t += kBT) ghist[blockIdx.x * kNB + t] = h[t];
}

// ---- Pass 2: per-bucket exclusive scan across blocks (one block per bucket) ----
__global__ __launch_bounds__(kBT) void k_scan_blocks(int* __restrict__ ghist,
                                                     int* __restrict__ totals) {
    const int b = blockIdx.x;
    __shared__ int sums[kBT];
    constexpr int per = kNBLK / kBT;   // 8
    const int base = threadIdx.x * per;
    int local[per];
    int s = 0;
    for (int k = 0; k < per; ++k) { local[k] = ghist[(base + k) * kNB + b]; s += local[k]; }
    sums[threadIdx.x] = s;
    __syncthreads();
    for (int off = 1; off < kBT; off <<= 1) {           // Hillis-Steele inclusive
        int t = (threadIdx.x >= off) ? sums[threadIdx.x - off] : 0;
        __syncthreads();
        sums[threadIdx.x] += t;
        __syncthreads();
    }
    int run = sums[threadIdx.x] - s;                    // exclusive base for this chunk
    for (int k = 0; k < per; ++k) { const int c = local[k]; ghist[(base + k) * kNB + b] = run; run += c; }
    if (threadIdx.x == kBT - 1) totals[b] = sums[kBT - 1];
}

// ---- Pass 3: exclusive scan of bucket totals -> bases (+ grand total) ----
__global__ __launch_bounds__(kNB) void k_scan_buckets(const int* __restrict__ totals,
                                                      int* __restrict__ bases) {
    __shared__ int s[kNB];
    const int t = threadIdx.x;
    const int own = totals[t];
    s[t] = own;
    __syncthreads();
    for (int off = 1; off < kNB; off <<= 1) {
        int v = (t >= off) ? s[t - off] : 0;
        __syncthreads();
        s[t] += v;
        __syncthreads();
    }
    bases[t] = s[t] - own;
    if (t == kNB - 1) bases[kNB] = s[kNB - 1];          // total masked count
}

// ---- Pass 4 (REWRITTEN): LDS-staged block counting sort by i0, then
//      contiguous-run flush so each wave-store instruction coalesces. ----
__global__ __launch_bounds__(kBT) void k_scatter0(const float* __restrict__ x,
                                                  const float* __restrict__ dir, int M,
                                                  const int* __restrict__ ghist,
                                                  const int* __restrict__ bases,
                                                  float4* __restrict__ payl0,
                                                  int* __restrict__ vox0) {
    __shared__ float4 sPay[kTile];     // 32 KB
    __shared__ int    sVox[kTile];     //  8 KB
    __shared__ int    sGidx[kTile];    //  8 KB
    __shared__ int    h[kNB];          // hist -> inclusive scan (in place)
    __shared__ int    lbase[kNB];      // local exclusive base per bucket
    __shared__ int    cur[kNB];        // local rank cursors
    __shared__ int    cntSh;           // masked count in this block

    const int t = threadIdx.x;
    h[t] = 0; cur[t] = 0;
    __syncthreads();

    const int stride = kNBLK * kBT;
    const int base = blockIdx.x * kBT + t;

    // Pass A: classify, count (voff cached in registers; -1 = unmasked)
    int pvox[kIt];
    #pragma unroll
    for (int it = 0; it < kIt; ++it) {
        pvox[it] = -1;
        const int i = base + it * stride;
        if (i < M) {
            const float x0 = x[3 * i + 0];
            const float x1 = x[3 * i + 1];
            const float x2 = x[3 * i + 2];
            int b, voff;
            if (point_to_voxel(x0, x1, x2, b, voff)) {
                pvox[it] = voff;
                atomicAdd(&h[b], 1);
            }
        }
    }
    __syncthreads();

    // Exclusive scan of h[256] with 256 threads (inclusive in place)
    const int own = h[t];
    __syncthreads();
    for (int off = 1; off < kNB; off <<= 1) {
        const int u = (t >= off) ? h[t - off] : 0;
        __syncthreads();
        h[t] += u;
        __syncthreads();
    }
    lbase[t] = h[t] - own;
    if (t == kNB - 1) cntSh = h[kNB - 1];
    __syncthreads();

    // Pass B: stage records bucket-sorted in LDS + precompute global index
    #pragma unroll
    for (int it = 0; it < kIt; ++it) {
        const int voff = pvox[it];
        if (voff >= 0) {
            const int i = base + it * stride;
            const int b = voff / (kN * kN);                 // i0
            const int r = atomicAdd(&cur[b], 1);            // LDS atomic
            const int lpos = lbase[b] + r;
            sPay[lpos] = make_float4(dir[3 * i + 0], dir[3 * i + 1], dir[3 * i + 2],
                                     __int_as_float(i));
            sVox[lpos]  = voff;
            sGidx[lpos] = bases[b] + ghist[blockIdx.x * kNB + b] + r;
        }
    }
    __syncthreads();

    // Flush: consecutive lanes -> consecutive global slots within bucket runs
    const int cnt = cntSh;
    for (int s = t; s < cnt; s += kBT) {
        const int g = sGidx[s];
        payl0[g] = sPay[s];
        vox0[g]  = sVox[s];
    }
}

// ---- Stage B1: per-(slab,chunk) i1 histogram (reads vox0 only) ----
__global__ __launch_bounds__(kBT) void k_hist1(const int* __restrict__ vox0,
                                               const int* __restrict__ bases,
                                               int* __restrict__ ghist2) {
    const int s = blockIdx.x / kC;
    const int c = blockIdx.x % kC;
    const int beg = bases[s];
    const int len = bases[s + 1] - beg;
    const int lo = beg + (int)(((long long)len * c) / kC);
    const int hi = beg + (int)(((long long)len * (c + 1)) / kC);

    __shared__ int h[kN];
    for (int t = threadIdx.x; t < kN; t += kBT) h[t] = 0;
    __syncthreads();
    for (int j = lo + threadIdx.x; j < hi; j += kBT) {
        const int i1 = (vox0[j] / kN) % kN;
        atomicAdd(&h[i1], 1);
    }
    __syncthreads();
    for (int t = threadIdx.x; t < kN; t += kBT)
        ghist2[(size_t)blockIdx.x * kN + t] = h[t];
}

// ---- Stage B2: per-slab scan over (i1, chunk) -> absolute cursors ----
__global__ __launch_bounds__(kBT) void k_scan1(int* __restrict__ ghist2,
                                               const int* __restrict__ bases) {
    const int s = blockIdx.x;          // slab
    const int t = threadIdx.x;
    __shared__ int sc[kBT];

    int v[kC];
    int tot = 0;
    if (t < kN) {
        for (int c = 0; c < kC; ++c) {
            v[c] = ghist2[(size_t)(s * kC + c) * kN + t];
            tot += v[c];
        }
    }
    sc[t] = (t < kN) ? tot : 0;
    __syncthreads();
    for (int off = 1; off < kBT; off <<= 1) {          // inclusive scan over i1
        const int u = (t >= off) ? sc[t - off] : 0;
        __syncthreads();
        sc[t] += u;
        __syncthreads();
    }
    if (t < kN) {
        int off0 = bases[s] + sc[t] - tot;             // exclusive base for this i1
        for (int c = 0; c < kC; ++c) {
            ghist2[(size_t)(s * kC + c) * kN + t] = off0;
            off0 += v[c];
        }
    }
}

// ---- Stage B3: per-chunk LDS-cursor scatter into (i0,i1)-grouped arrays ----
__global__ __launch_bounds__(kBT) void k_scatter1(const float4* __restrict__ payl0,
                                                  const int* __restrict__ vox0,
                                                  float4* __restrict__ payl1,
                                                  int* __restrict__ vox1,
                                                  const int* __restrict__ bases,
                                                  const int* __restrict__ ghist2) {
    const int s = blockIdx.x / kC;
    const int c = blockIdx.x % kC;
    const int beg = bases[s];
    const int len = bases[s + 1] - beg;
    const int lo = beg + (int)(((long long)len * c) / kC);
    const int hi = beg + (int)(((long long)len * (c + 1)) / kC);

    __shared__ int cur[kN];
    for (int t = threadIdx.x; t < kN; t += kBT)
        cur[t] = ghist2[(size_t)blockIdx.x * kN + t];
    __syncthreads();
    for (int j = lo + threadIdx.x; j < hi; j += kBT) {
        const int v  = vox0[j];
        const int i1 = (v / kN) % kN;
        const int pos = atomicAdd(&cur[i1], 1);        // LDS atomic
        payl1[pos] = payl0[j];
        vox1[pos]  = v;
    }
}

// ---- Pass 6: address-ordered gather + SH eval over the sorted list ----
__global__ __launch_bounds__(kBT) void k_gather(const float4* __restrict__ payload,
                                                const int* __restrict__ voxarr,
                                                const float* __restrict__ grid,
                                                float* __restrict__ out, int M,
                                                const int* __restrict__ bases) {
    const int j = blockIdx.x * kBT + threadIdx.x;
    if (j >= bases[kNB]) return;

    const float4 p = payload[j];
    const int i = __float_as_int(p.w);
    const size_t voff = (size_t)voxarr[j] * 28u;
    const float4* __restrict__ g4 = reinterpret_cast<const float4*>(grid + voff);
    const float4 t0 = g4[0];
    const float4 t1 = g4[1];
    const float4 t2 = g4[2];
    const float4 t3 = g4[3];
    const float4 t4 = g4[4];
    const float4 t5 = g4[5];
    const float4 t6 = g4[6];
    const float t[28] = {
        t0.x, t0.y, t0.z, t0.w,
        t1.x, t1.y, t1.z, t1.w,
        t2.x, t2.y, t2.z, t2.w,
        t3.x, t3.y, t3.z, t3.w,
        t4.x, t4.y, t4.z, t4.w,
        t5.x, t5.y, t5.z, t5.w,
        t6.x, t6.y, t6.z, t6.w
    };

    const float sg = fmaxf(t[0], 0.0f);

    const float dx = p.x, dy = p.y, dz = p.z;
    const float b0 = 0.282095f;
    const float b1 = -0.488603f * dy;
    const float b2 =  0.488603f * dz;
    const float b3 = -0.488603f * dx;
    const float b4 =  1.092548f * dx * dy;
    const float b5 = -1.092548f * dy * dz;
    const float b6 =  0.315392f * (2.0f * dz * dz - dx * dx - dy * dy);
    const float b7 = -1.092548f * dx * dz;
    const float b8 =  0.546274f * (dx * dx - dy * dy);

    const float c0 = b0 * t[1]  + b1 * t[2]  + b2 * t[3]  + b3 * t[4]  + b4 * t[5]
                   + b5 * t[6]  + b6 * t[7]  + b7 * t[8]  + b8 * t[9];
    const float c1 = b0 * t[10] + b1 * t[11] + b2 * t[12] + b3 * t[13] + b4 * t[14]
                   + b5 * t[15] + b6 * t[16] + b7 * t[17] + b8 * t[18];
    const float c2 = b0 * t[19] + b1 * t[20] + b2 * t[21] + b3 * t[22] + b4 * t[23]
                   + b5 * t[24] + b6 * t[25] + b7 * t[26] + b8 * t[27];

    out[3 * i + 0] = c0;
    out[3 * i + 1] = c1;
    out[3 * i + 2] = c2;
    out[(size_t)3 * M + i] = sg;
}

// ---- Fallback: the original verified single-kernel path ----
__global__ __launch_bounds__(kBT) void nerf_fwd(
    const float* __restrict__ x,
    const float* __restrict__ dir,
    const float* __restrict__ grid,
    float* __restrict__ out, int M)
{
    int i = blockIdx.x * blockDim.x + threadIdx.x;
    if (i >= M) return;

    const float x0 = x[3 * i + 0];
    const float x1 = x[3 * i + 1];
    const float x2 = x[3 * i + 2];

    float c0 = 0.0f, c1 = 0.0f, c2 = 0.0f, sg = 0.0f;
    int b, voff;
    if (point_to_voxel(x0, x1, x2, b, voff)) {
        const float4* __restrict__ g4 = reinterpret_cast<const float4*>(grid + (size_t)voff * 28u);
        const float4 t0 = g4[0], t1 = g4[1], t2 = g4[2], t3 = g4[3], t4 = g4[4], t5 = g4[5], t6 = g4[6];
        const float t[28] = {
            t0.x, t0.y, t0.z, t0.w, t1.x, t1.y, t1.z, t1.w, t2.x, t2.y, t2.z, t2.w,
            t3.x, t3.y, t3.z, t3.w, t4.x, t4.y, t4.z, t4.w, t5.x, t5.y, t5.z, t5.w,
            t6.x, t6.y, t6.z, t6.w
        };
        sg = fmaxf(t[0], 0.0f);
        const float dx = dir[3 * i + 0], dy = dir[3 * i + 1], dz = dir[3 * i + 2];
        const float b0 = 0.282095f;
        const float b1 = -0.488603f * dy;
        const float b2 =  0.488603f * dz;
        const float b3 = -0.488603f * dx;
        const float b4 =  1.092548f * dx * dy;
        const float b5 = -1.092548f * dy * dz;
        const float b6 =  0.315392f * (2.0f * dz * dz - dx * dx - dy * dy);
        const float b7 = -1.092548f * dx * dz;
        const float b8 =  0.546274f * (dx * dx - dy * dy);
        c0 = b0*t[1]  + b1*t[2]  + b2*t[3]  + b3*t[4]  + b4*t[5]  + b5*t[6]  + b6*t[7]  + b7*t[8]  + b8*t[9];
        c1 = b0*t[10] + b1*t[11] + b2*t[12] + b3*t[13] + b4*t[14] + b5*t[15] + b6*t[16] + b7*t[17] + b8*t[18];
        c2 = b0*t[19] + b1*t[20] + b2*t[21] + b3*t[22] + b4*t[23] + b5*t[24] + b6*t[25] + b7*t[26] + b8*t[27];
    }
    out[3 * i + 0] = c0;
    out[3 * i + 1] = c1;
    out[3 * i + 2] = c2;
    out[(size_t)3 * M + i] = sg;
}

extern "C" void kernel_launch(void* const* d_in, const int* in_sizes, int n_in,
                              void* d_out, int out_size, void* d_ws, size_t ws_size,
                              hipStream_t stream) {
    const float* x    = (const float*)d_in[0];
    const float* dir  = (const float*)d_in[1];
    const float* grid = (const float*)d_in[2];
    float* out = (float*)d_out;

    const int M = in_sizes[0] / 3;   // 4194304

    // Workspace: payl0 (M f4) | payl1 (M f4) | vox0 (M int) | vox1 (M int)
    //          | ghist (kNBLK*kNB) | totals (kNB) | bases (kNB+1)
    //          | ghist2 (kN*kC*kN)                                   ~= 173 MB
    const size_t need = (size_t)M * 16 * 2 + (size_t)M * 4 * 2
                      + (size_t)kNBLK * kNB * 4 + (size_t)(2 * kNB + 1) * 4
                      + (size_t)kN * kC * kN * 4;
    // staged scatter assumes M <= kNBLK*kBT*kIt (exact for 4194304)
    if (d_ws == nullptr || ws_size < need || M > kNBLK * kBT * kIt) {
        const int grid_dim = (M + kBT - 1) / kBT;
        nerf_fwd<<<grid_dim, kBT, 0, stream>>>(x, dir, grid, out, M);
        return;
    }

    float4* payl0 = (float4*)d_ws;
    float4* payl1 = payl0 + M;
    int* vox0   = (int*)(payl1 + M);
    int* vox1   = vox0 + M;
    int* ghist  = vox1 + M;
    int* totals = ghist + (size_t)kNBLK * kNB;
    int* bases  = totals + kNB;
    int* ghist2 = bases + (kNB + 1);

    k_count      <<<kNBLK, kBT, 0, stream>>>(x, out, M, ghist);
    k_scan_blocks<<<kNB,   kBT, 0, stream>>>(ghist, totals);
    k_scan_buckets<<<1,    kNB, 0, stream>>>(totals, bases);
    k_scatter0   <<<kNBLK, kBT, 0, stream>>>(x, dir, M, ghist, bases, payl0, vox0);
    k_hist1      <<<kN * kC, kBT, 0, stream>>>(vox0, bases, ghist2);
    k_scan1      <<<kN,    kBT, 0, stream>>>(ghist2, bases);
    k_scatter1   <<<kN * kC, kBT, 0, stream>>>(payl0, vox0, payl1, vox1, bases, ghist2);
    k_gather     <<<(M + kBT - 1) / kBT, kBT, 0, stream>>>(payl1, vox1, grid, out, M, bases);
}

// Round 7
// 1189.446 us; speedup vs baseline: 1.0568x; 1.0378x over previous
//
#include <hip/hip_runtime.h>

// NerfModel: voxel-grid gather + SH-deg2 eval.
//   inputs : x (M,3) f32, d (M,3) f32, voxel_grid (200,200,200,28) f32
//   outputs: color (M,3) f32 then sigma (M,) f32, concatenated in d_out.
//
// Ladder:
//   R0 1087us  single-kernel random gather (random-DRAM read regime).
//   R2 1291us  (i0,i1) sort: gather fixed (~300) but scatter = 945.
//   R3/R5/R6 1256/1257/1234: every scatter variant ~equal =>
//     the cost is ~1.77M PARTIAL-LINE scattered writes (write-allocate RMW
//     at DRAM latency), not atomics and not instruction-level coalescing.
//     Also R1 (1216, no stage B) < R3..R6 => stage B net-negative. Dropped.
//   R7 (this): eliminate partial-line writes:
//     - full-line streaming memset of out (replaces divergent zeroing)
//     - scatter with 8192-pt contiguous tiles staged in LDS: bucket runs
//       ~24 records (~380B) -> wave-stores become ~3 full-line bursts
//     - gather over i0-sorted list (no stage B)

constexpr float kScale = 1.5f;
constexpr int   kN     = 200;
constexpr int   kNB    = 256;            // i0 buckets (200 used)
constexpr int   kBT    = 256;            // threads per block
constexpr int   kTILE  = 8192;           // points per contiguous tile
constexpr int   kIT    = kTILE / kBT;    // 32 points per thread
constexpr int   kMaxPer = 8;             // scan_blocks supports nT <= kBT*kMaxPer

__device__ __forceinline__ bool point_to_voxel(float x0, float x1, float x2,
                                               int& bucket, int& voff) {
    const bool mask = (fabsf(x0) < kScale) && (fabsf(x1) < kScale) && (fabsf(x2) < kScale);
    if (!mask) return false;
    const float h = 2.0f * kScale / (float)kN;   // 0.015f
    int i0 = (int)(x0 / h + 0.5f * (float)kN);
    int i1 = (int)(x1 / h + 0.5f * (float)kN);
    int i2 = (int)(x2 / h + 0.5f * (float)kN);
    i0 = min(max(i0, 0), kN - 1);
    i1 = min(max(i1, 0), kN - 1);
    i2 = min(max(i2, 0), kN - 1);
    bucket = i0;
    voff   = (i0 * kN + i1) * kN + i2;
    return true;
}

// ---- Pass 0: full-line streaming zero of the whole output (4M floats) ----
__global__ __launch_bounds__(kBT) void k_zero_out(float4* __restrict__ out4, int n4) {
    const int stride = gridDim.x * kBT;
    for (int i = blockIdx.x * kBT + threadIdx.x; i < n4; i += stride)
        out4[i] = make_float4(0.0f, 0.0f, 0.0f, 0.0f);
}

// ---- Pass 1: per-tile i0 histogram (contiguous tiles; NO output writes) ----
__global__ __launch_bounds__(kBT) void k_count(const float* __restrict__ x, int M,
                                               int* __restrict__ ghist) {
    __shared__ int h[kNB];
    h[threadIdx.x] = 0;
    __syncthreads();
    const int tb = blockIdx.x * kTILE;
    #pragma unroll
    for (int k = 0; k < kIT; ++k) {
        const int i = tb + k * kBT + threadIdx.x;
        if (i < M) {
            int b, voff;
            if (point_to_voxel(x[3 * i + 0], x[3 * i + 1], x[3 * i + 2], b, voff))
                atomicAdd(&h[b], 1);
        }
    }
    __syncthreads();
    ghist[blockIdx.x * kNB + threadIdx.x] = h[threadIdx.x];
}

// ---- Pass 2: per-bucket exclusive scan across tiles (one block per bucket) ----
__global__ __launch_bounds__(kBT) void k_scan_blocks(int* __restrict__ ghist,
                                                     int* __restrict__ totals, int nT) {
    const int b = blockIdx.x;
    __shared__ int sums[kBT];
    const int per = (nT + kBT - 1) / kBT;   // <= kMaxPer (launcher-guaranteed)
    const int base = threadIdx.x * per;
    int local[kMaxPer];
    int s = 0;
    for (int k = 0; k < per; ++k) {
        const int idx = base + k;
        local[k] = (idx < nT) ? ghist[idx * kNB + b] : 0;
        s += local[k];
    }
    sums[threadIdx.x] = s;
    __syncthreads();
    for (int off = 1; off < kBT; off <<= 1) {           // Hillis-Steele inclusive
        int t = (threadIdx.x >= off) ? sums[threadIdx.x - off] : 0;
        __syncthreads();
        sums[threadIdx.x] += t;
        __syncthreads();
    }
    int run = sums[threadIdx.x] - s;                    // exclusive base for this chunk
    for (int k = 0; k < per; ++k) {
        const int idx = base + k;
        if (idx < nT) ghist[idx * kNB + b] = run;
        run += local[k];
    }
    if (threadIdx.x == kBT - 1) totals[b] = sums[kBT - 1];
}

// ---- Pass 3: exclusive scan of bucket totals -> bases (+ grand total) ----
__global__ __launch_bounds__(kNB) void k_scan_buckets(const int* __restrict__ totals,
                                                      int* __restrict__ bases) {
    __shared__ int s[kNB];
    const int t = threadIdx.x;
    const int own = totals[t];
    s[t] = own;
    __syncthreads();
    for (int off = 1; off < kNB; off <<= 1) {
        int v = (t >= off) ? s[t - off] : 0;
        __syncthreads();
        s[t] += v;
        __syncthreads();
    }
    bases[t] = s[t] - own;
    if (t == kNB - 1) bases[kNB] = s[kNB - 1];          // total masked count
}

// ---- Pass 4: big-tile LDS-staged counting sort by i0, long-run flush ----
__global__ __launch_bounds__(kBT) void k_scatter0(const float* __restrict__ x,
                                                  const float* __restrict__ dir, int M,
                                                  const int* __restrict__ ghist,
                                                  const int* __restrict__ bases,
                                                  float4* __restrict__ payl0,
                                                  int* __restrict__ vox0) {
    __shared__ int sIdx[kTILE];    // 32 KB: absolute point index, bucket-sorted
    __shared__ int sVox[kTILE];    // 32 KB: voxel record index
    __shared__ int h[kNB];         // hist -> inclusive scan (in place)
    __shared__ int lb[kNB];        // local exclusive base per bucket
    __shared__ int cur[kNB];       // local rank cursors
    __shared__ int gb[kNB];        // global destination base per bucket
    __shared__ int cntSh;

    const int t = threadIdx.x;
    h[t] = 0; cur[t] = 0;
    __syncthreads();

    const int tb = blockIdx.x * kTILE;

    // Phase 1: classify + count; cache voff in registers (-1 = unmasked)
    int pvox[kIT];
    #pragma unroll
    for (int k = 0; k < kIT; ++k) {
        pvox[k] = -1;
        const int i = tb + k * kBT + t;
        if (i < M) {
            int b, voff;
            if (point_to_voxel(x[3 * i + 0], x[3 * i + 1], x[3 * i + 2], b, voff))
                pvox[k] = voff;
        }
        if (pvox[k] >= 0) atomicAdd(&h[pvox[k] / (kN * kN)], 1);
    }
    __syncthreads();

    // Phase 2: exclusive scan of h (inclusive in place), bases into LDS
    const int own = h[t];
    __syncthreads();
    for (int off = 1; off < kNB; off <<= 1) {
        const int u = (t >= off) ? h[t - off] : 0;
        __syncthreads();
        h[t] += u;
        __syncthreads();
    }
    lb[t] = h[t] - own;
    gb[t] = bases[t] + ghist[blockIdx.x * kNB + t];
    if (t == kNB - 1) cntSh = h[kNB - 1];
    __syncthreads();

    // Phase 3: stage (index, voff) bucket-sorted in LDS
    #pragma unroll
    for (int k = 0; k < kIT; ++k) {
        const int voff = pvox[k];
        if (voff >= 0) {
            const int b = voff / (kN * kN);
            const int r = atomicAdd(&cur[b], 1);       // LDS atomic
            const int p = lb[b] + r;
            sIdx[p] = tb + k * kBT + t;
            sVox[p] = voff;
        }
    }
    __syncthreads();

    // Phase 4: flush in sorted order -> long contiguous runs (~24 recs ~ 380 B)
    const int cnt = cntSh;
    for (int s = t; s < cnt; s += kBT) {
        const int voff = sVox[s];
        const int b = voff / (kN * kN);
        const int g = gb[b] + (s - lb[b]);
        const int i = sIdx[s];
        payl0[g] = make_float4(dir[3 * i + 0], dir[3 * i + 1], dir[3 * i + 2],
                               __int_as_float(i));
        vox0[g]  = voff;
    }
}

// ---- Pass 5: address-ordered gather + SH eval over the i0-sorted list ----
__global__ __launch_bounds__(kBT) void k_gather(const float4* __restrict__ payload,
                                                const int* __restrict__ voxarr,
                                                const float* __restrict__ grid,
                                                float* __restrict__ out, int M,
                                                const int* __restrict__ bases) {
    const int j = blockIdx.x * kBT + threadIdx.x;
    if (j >= bases[kNB]) return;

    const float4 p = payload[j];
    const int i = __float_as_int(p.w);
    const size_t voff = (size_t)voxarr[j] * 28u;
    const float4* __restrict__ g4 = reinterpret_cast<const float4*>(grid + voff);
    const float4 t0 = g4[0];
    const float4 t1 = g4[1];
    const float4 t2 = g4[2];
    const float4 t3 = g4[3];
    const float4 t4 = g4[4];
    const float4 t5 = g4[5];
    const float4 t6 = g4[6];
    const float t[28] = {
        t0.x, t0.y, t0.z, t0.w,
        t1.x, t1.y, t1.z, t1.w,
        t2.x, t2.y, t2.z, t2.w,
        t3.x, t3.y, t3.z, t3.w,
        t4.x, t4.y, t4.z, t4.w,
        t5.x, t5.y, t5.z, t5.w,
        t6.x, t6.y, t6.z, t6.w
    };

    const float sg = fmaxf(t[0], 0.0f);

    const float dx = p.x, dy = p.y, dz = p.z;
    const float b0 = 0.282095f;
    const float b1 = -0.488603f * dy;
    const float b2 =  0.488603f * dz;
    const float b3 = -0.488603f * dx;
    const float b4 =  1.092548f * dx * dy;
    const float b5 = -1.092548f * dy * dz;
    const float b6 =  0.315392f * (2.0f * dz * dz - dx * dx - dy * dy);
    const float b7 = -1.092548f * dx * dz;
    const float b8 =  0.546274f * (dx * dx - dy * dy);

    const float c0 = b0 * t[1]  + b1 * t[2]  + b2 * t[3]  + b3 * t[4]  + b4 * t[5]
                   + b5 * t[6]  + b6 * t[7]  + b7 * t[8]  + b8 * t[9];
    const float c1 = b0 * t[10] + b1 * t[11] + b2 * t[12] + b3 * t[13] + b4 * t[14]
                   + b5 * t[15] + b6 * t[16] + b7 * t[17] + b8 * t[18];
    const float c2 = b0 * t[19] + b1 * t[20] + b2 * t[21] + b3 * t[22] + b4 * t[23]
                   + b5 * t[24] + b6 * t[25] + b7 * t[26] + b8 * t[27];

    out[3 * i + 0] = c0;
    out[3 * i + 1] = c1;
    out[3 * i + 2] = c2;
    out[(size_t)3 * M + i] = sg;
}

// ---- Fallback: the original verified single-kernel path ----
__global__ __launch_bounds__(kBT) void nerf_fwd(
    const float* __restrict__ x,
    const float* __restrict__ dir,
    const float* __restrict__ grid,
    float* __restrict__ out, int M)
{
    int i = blockIdx.x * blockDim.x + threadIdx.x;
    if (i >= M) return;

    const float x0 = x[3 * i + 0];
    const float x1 = x[3 * i + 1];
    const float x2 = x[3 * i + 2];

    float c0 = 0.0f, c1 = 0.0f, c2 = 0.0f, sg = 0.0f;
    int b, voff;
    if (point_to_voxel(x0, x1, x2, b, voff)) {
        const float4* __restrict__ g4 = reinterpret_cast<const float4*>(grid + (size_t)voff * 28u);
        const float4 t0 = g4[0], t1 = g4[1], t2 = g4[2], t3 = g4[3], t4 = g4[4], t5 = g4[5], t6 = g4[6];
        const float t[28] = {
            t0.x, t0.y, t0.z, t0.w, t1.x, t1.y, t1.z, t1.w, t2.x, t2.y, t2.z, t2.w,
            t3.x, t3.y, t3.z, t3.w, t4.x, t4.y, t4.z, t4.w, t5.x, t5.y, t5.z, t5.w,
            t6.x, t6.y, t6.z, t6.w
        };
        sg = fmaxf(t[0], 0.0f);
        const float dx = dir[3 * i + 0], dy = dir[3 * i + 1], dz = dir[3 * i + 2];
        const float b0 = 0.282095f;
        const float b1 = -0.488603f * dy;
        const float b2 =  0.488603f * dz;
        const float b3 = -0.488603f * dx;
        const float b4 =  1.092548f * dx * dy;
        const float b5 = -1.092548f * dy * dz;
        const float b6 =  0.315392f * (2.0f * dz * dz - dx * dx - dy * dy);
        const float b7 = -1.092548f * dx * dz;
        const float b8 =  0.546274f * (dx * dx - dy * dy);
        c0 = b0*t[1]  + b1*t[2]  + b2*t[3]  + b3*t[4]  + b4*t[5]  + b5*t[6]  + b6*t[7]  + b7*t[8]  + b8*t[9];
        c1 = b0*t[10] + b1*t[11] + b2*t[12] + b3*t[13] + b4*t[14] + b5*t[15] + b6*t[16] + b7*t[17] + b8*t[18];
        c2 = b0*t[19] + b1*t[20] + b2*t[21] + b3*t[22] + b4*t[23] + b5*t[24] + b6*t[25] + b7*t[26] + b8*t[27];
    }
    out[3 * i + 0] = c0;
    out[3 * i + 1] = c1;
    out[3 * i + 2] = c2;
    out[(size_t)3 * M + i] = sg;
}

extern "C" void kernel_launch(void* const* d_in, const int* in_sizes, int n_in,
                              void* d_out, int out_size, void* d_ws, size_t ws_size,
                              hipStream_t stream) {
    const float* x    = (const float*)d_in[0];
    const float* dir  = (const float*)d_in[1];
    const float* grid = (const float*)d_in[2];
    float* out = (float*)d_out;

    const int M  = in_sizes[0] / 3;              // 4194304
    const int nT = (M + kTILE - 1) / kTILE;      // 512 tiles

    // Workspace: payl0 (M f4) | vox0 (M int) | ghist (nT*kNB) | totals | bases  ~= 84.5 MB
    const size_t need = (size_t)M * 16 + (size_t)M * 4
                      + (size_t)nT * kNB * 4 + (size_t)(2 * kNB + 1) * 4;
    if (d_ws == nullptr || ws_size < need || nT > kBT * kMaxPer) {
        const int grid_dim = (M + kBT - 1) / kBT;
        nerf_fwd<<<grid_dim, kBT, 0, stream>>>(x, dir, grid, out, M);
        return;
    }

    float4* payl0 = (float4*)d_ws;
    int* vox0   = (int*)(payl0 + M);
    int* ghist  = vox0 + M;
    int* totals = ghist + (size_t)nT * kNB;
    int* bases  = totals + kNB;

    k_zero_out   <<<2048, kBT, 0, stream>>>((float4*)out, M);   // 4M floats = M float4
    k_count      <<<nT,   kBT, 0, stream>>>(x, M, ghist);
    k_scan_blocks<<<kNB,  kBT, 0, stream>>>(ghist, totals, nT);
    k_scan_buckets<<<1,   kNB, 0, stream>>>(totals, bases);
    k_scatter0   <<<nT,   kBT, 0, stream>>>(x, dir, M, ghist, bases, payl0, vox0);
    k_gather     <<<(M + kBT - 1) / kBT, kBT, 0, stream>>>(payl0, vox0, grid, out, M, bases);
}

// Round 9
// 1099.975 us; speedup vs baseline: 1.1427x; 1.0813x over previous
//
#include <hip/hip_runtime.h>

// NerfModel: voxel-grid gather + SH-deg2 eval.
//   inputs : x (M,3) f32, d (M,3) f32, voxel_grid (200,200,200,28) f32
//   outputs: color (M,3) f32 then sigma (M,) f32, concatenated in d_out.
//
// Ladder summary:
//   R0 1087us  per-thread float4 random gather.
//   R1-R7 1189-1291us: every sort-then-gather pipeline loses; sort tax ~= gather win.
//   R8 coop fused sort: cooperative launch silently no-ops under graph capture
//      (absmax 0.365 == max|ref color| -> output all zeros). Coop is dead here.
//   R9 (this): back to the verified single-kernel, but COOPERATIVE RECORD LOADS.
//     Hypothesis: R0 is VMEM-coalescing bound (64 lanes -> 64 lines per load
//     instruction, ~12.4M uncoalesced wave-instructions ~ 1.1ms). Fix: compact
//     masked points in LDS, then consecutive lanes load consecutive 16B slots of
//     the same 112B record (7 lanes/record -> ~18 transactions per instruction
//     instead of 64). Records staged in LDS (stride 29 floats: coprime with 32
//     banks), SH computed from LDS with identical arithmetic.

constexpr float kScale = 1.5f;
constexpr int   kN     = 200;
constexpr int   kBT    = 256;    // threads per block
constexpr int   kPad   = 29;     // LDS row stride in floats (gcd(29,32)=1)

__global__ __launch_bounds__(kBT) void nerf_fwd2(
    const float* __restrict__ x,
    const float* __restrict__ dir,
    const float* __restrict__ g,
    float* __restrict__ out, int M)
{
    __shared__ float sdata[kBT * kPad];   // 29.7 KB record staging
    __shared__ int   svoff[kBT];          // compacted voxel record ids
    __shared__ int   scan[kBT];           // mask prefix-sum scratch
    __shared__ int   nmSh;

    const int tid = threadIdx.x;
    const int i   = blockIdx.x * kBT + tid;

    // ---- Phase 1: classify own point (x, dir reads coalesced) ----
    bool  m = false;
    int   voff = 0;
    float dx = 0.0f, dy = 0.0f, dz = 0.0f;
    if (i < M) {
        const float x0 = x[3 * i + 0];
        const float x1 = x[3 * i + 1];
        const float x2 = x[3 * i + 2];
        m = (fabsf(x0) < kScale) && (fabsf(x1) < kScale) && (fabsf(x2) < kScale);
        if (m) {
            const float h = 2.0f * kScale / (float)kN;   // 0.015f
            int i0 = (int)(x0 / h + 0.5f * (float)kN);
            int i1 = (int)(x1 / h + 0.5f * (float)kN);
            int i2 = (int)(x2 / h + 0.5f * (float)kN);
            i0 = min(max(i0, 0), kN - 1);
            i1 = min(max(i1, 0), kN - 1);
            i2 = min(max(i2, 0), kN - 1);
            voff = (i0 * kN + i1) * kN + i2;
            dx = dir[3 * i + 0];
            dy = dir[3 * i + 1];
            dz = dir[3 * i + 2];
        } else {
            out[3 * i + 0] = 0.0f;
            out[3 * i + 1] = 0.0f;
            out[3 * i + 2] = 0.0f;
            out[(size_t)3 * M + i] = 0.0f;
        }
    }

    // ---- Phase 2: block-level compaction of masked points ----
    scan[tid] = m ? 1 : 0;
    __syncthreads();
    for (int off = 1; off < kBT; off <<= 1) {            // Hillis-Steele inclusive
        const int v = (tid >= off) ? scan[tid - off] : 0;
        __syncthreads();
        scan[tid] += v;
        __syncthreads();
    }
    const int pos = scan[tid] - (m ? 1 : 0);             // exclusive rank
    if (tid == kBT - 1) nmSh = scan[kBT - 1];
    if (m) svoff[pos] = voff;
    __syncthreads();
    const int nm = nmSh;

    // ---- Phase 3: cooperative staged load of nm records (7 float4 each) ----
    // Linear slot l -> (rec = l/7, slot = l%7): consecutive lanes read
    // consecutive 16B of the SAME record -> ~2 lines per record per instruction.
    const int total = nm * 7;
    for (int l = tid; l < total; l += kBT) {
        const int rec  = l / 7;                          // magic-mul division
        const int slot = l - rec * 7;
        const float4 v = *reinterpret_cast<const float4*>(
            g + (size_t)svoff[rec] * 28u + (size_t)slot * 4u);
        float* dst = &sdata[rec * kPad + slot * 4];
        dst[0] = v.x; dst[1] = v.y; dst[2] = v.z; dst[3] = v.w;
    }
    __syncthreads();

    // ---- Phase 4: SH eval from LDS (identical arithmetic to verified R0) ----
    if (m) {
        const float* t = &sdata[pos * kPad];

        const float sg = fmaxf(t[0], 0.0f);

        const float b0 = 0.282095f;
        const float b1 = -0.488603f * dy;
        const float b2 =  0.488603f * dz;
        const float b3 = -0.488603f * dx;
        const float b4 =  1.092548f * dx * dy;
        const float b5 = -1.092548f * dy * dz;
        const float b6 =  0.315392f * (2.0f * dz * dz - dx * dx - dy * dy);
        const float b7 = -1.092548f * dx * dz;
        const float b8 =  0.546274f * (dx * dx - dy * dy);

        const float c0 = b0 * t[1]  + b1 * t[2]  + b2 * t[3]  + b3 * t[4]  + b4 * t[5]
                       + b5 * t[6]  + b6 * t[7]  + b7 * t[8]  + b8 * t[9];
        const float c1 = b0 * t[10] + b1 * t[11] + b2 * t[12] + b3 * t[13] + b4 * t[14]
                       + b5 * t[15] + b6 * t[16] + b7 * t[17] + b8 * t[18];
        const float c2 = b0 * t[19] + b1 * t[20] + b2 * t[21] + b3 * t[22] + b4 * t[23]
                       + b5 * t[24] + b6 * t[25] + b7 * t[26] + b8 * t[27];

        out[3 * i + 0] = c0;
        out[3 * i + 1] = c1;
        out[3 * i + 2] = c2;
        out[(size_t)3 * M + i] = sg;
    }
}

extern "C" void kernel_launch(void* const* d_in, const int* in_sizes, int n_in,
                              void* d_out, int out_size, void* d_ws, size_t ws_size,
                              hipStream_t stream) {
    const float* x    = (const float*)d_in[0];
    const float* dir  = (const float*)d_in[1];
    const float* grid = (const float*)d_in[2];
    float* out = (float*)d_out;

    const int M = in_sizes[0] / 3;   // 4194304
    const int grid_dim = (M + kBT - 1) / kBT;
    nerf_fwd2<<<grid_dim, kBT, 0, stream>>>(x, dir, grid, out, M);
}